// Round 6
// baseline (127.446 us; speedup 1.0000x reference)
//
#include <hip/hip_runtime.h>
#include <hip/hip_bf16.h>

typedef __attribute__((ext_vector_type(4))) float  floatx4;
typedef __attribute__((ext_vector_type(2))) float  floatx2;
typedef __attribute__((ext_vector_type(8))) __bf16 bf16x8;

#define FP8_MAX 448.0f

// HW OCP e4m3fn round-trip (RNE), matches ml_dtypes float8_e4m3fn for |v|<=448
__device__ __forceinline__ floatx2 fp8_qdq2(float a, float b) {
    int p = __builtin_amdgcn_cvt_pk_fp8_f32(a, b, 0, false);
    return __builtin_amdgcn_cvt_pk_f32_fp8(p, false);
}

__device__ __forceinline__ unsigned int f2bf(float f) {
    union { __hip_bfloat16 h; unsigned short u; } cv;
    cv.h = __float2bfloat16(f);
    return (unsigned int)cv.u;
}

__device__ __forceinline__ void async_copy16(void* lds, const void* g) {
    __builtin_amdgcn_global_load_lds(
        (const __attribute__((address_space(1))) unsigned int*)g,
        (__attribute__((address_space(3))) unsigned int*)lds, 16, 0, 0);
}

// ---------------------------------------------------------------------------
// Kernel 1: dequantize W [D=512][F=512] (quant blocks of 128 along F),
//           write transposed bf16 Wt [F=512][D=512].
__global__ void wdq_kernel(const float* __restrict__ W,
                           __hip_bfloat16* __restrict__ Wt) {
    const int D = 512, F = 512;
    int d = blockIdx.x;
    int t = threadIdx.x;
    float4 v = *reinterpret_cast<const float4*>(W + (size_t)d * F + t * 4);
    float am = fmaxf(fmaxf(fabsf(v.x), fabsf(v.y)), fmaxf(fabsf(v.z), fabsf(v.w)));
#pragma unroll
    for (int s = 16; s >= 1; s >>= 1) am = fmaxf(am, __shfl_xor(am, s));
    float scale = fmaxf(am, 1e-4f) / FP8_MAX;
    floatx2 d01 = fp8_qdq2(v.x / scale, v.y / scale);
    floatx2 d23 = fp8_qdq2(v.z / scale, v.w / scale);
    int f0 = t * 4;
    Wt[(size_t)(f0 + 0) * D + d] = __float2bfloat16(d01[0] * scale);
    Wt[(size_t)(f0 + 1) * D + d] = __float2bfloat16(d01[1] * scale);
    Wt[(size_t)(f0 + 2) * D + d] = __float2bfloat16(d23[0] * scale);
    Wt[(size_t)(f0 + 3) * D + d] = __float2bfloat16(d23[1] * scale);
}

// ---------------------------------------------------------------------------
// Kernel 2 (fused, persistent-B): each block owns a 128-col W panel for ALL K,
// staged in LDS ONCE (128 KB), then loops over 8 M-tiles of 128 rows.
// Main loop has NO VMEM wait at barriers: raw s_barrier + lgkmcnt(0) only.
// X f32 loads free-float across barriers (issued 2 k-steps ahead of quant,
// waits compiler-counted at consumption). As[128][64] single-buffered,
// 2 barriers per k-step; XOR-swizzled 16B slots (0 conflicts, rounds 3-4).
// ROUND-6 FIX: prologue quantX() BEFORE loadX(1) (round 5 clobbered v),
// and prologue vmcnt(8) -> vmcnt(0) (FIFO-count not hoist-proof).
__global__ __launch_bounds__(512, 1) void fused_gemm(
        const float* __restrict__ X,             // [M][512] f32
        const __hip_bfloat16* __restrict__ Wt,   // [512 f][512 k] bf16
        const float* __restrict__ bias,          // [512]
        float* __restrict__ C, int M) {
    const int K = 512, N = 512;
    __shared__ char Bs[131072];   // [128 f][512 k] bf16, swizzled 16B slots
    __shared__ char As[16384];    // [128 r][64 k]  bf16, swizzled 16B slots

    int bx  = blockIdx.x;
    int tN  = bx & 3;             // 4 N-panels of 128
    int mg  = bx >> 2;            // m-group: 1024 rows = 8 M-tiles of 128
    int tid = threadIdx.x, wid = tid >> 6, lane = tid & 63;
    int wm = wid >> 1, wn = wid & 1;   // 4x2 wave grid; wave tile 32(M)x64(N)
    int ar = tid >> 2, aq = tid & 3;   // A-quant: 4 thr/row, 32 f32 each

    const float* Xb = X + (size_t)mg * 1024 * K;
    const __hip_bfloat16* Wb = Wt + (size_t)tN * 128 * K;
    float* Cb = C + (size_t)mg * 1024 * N + tN * 128;

    float4 v[8];        // X stash: one 128-k quant block slice per thread
    uint4  q4[4];       // quantized bf16 (32 elems)
    floatx4 acc[2][4] = {};

    auto loadX = [&](int qb) {   // qb in [0,32): (mtile qb>>2, kblock qb&3)
        const float* src = Xb + ((size_t)(qb >> 2) * 128 + ar) * K
                              + (qb & 3) * 128 + aq * 32;
#pragma unroll
        for (int j = 0; j < 8; ++j)
            v[j] = *reinterpret_cast<const float4*>(src + j * 4);
    };
    auto quantX = [&]() {
        float am = 0.f;
#pragma unroll
        for (int j = 0; j < 8; ++j)
            am = fmaxf(am, fmaxf(fmaxf(fabsf(v[j].x), fabsf(v[j].y)),
                                 fmaxf(fabsf(v[j].z), fabsf(v[j].w))));
        am = fmaxf(am, __shfl_xor(am, 1));
        am = fmaxf(am, __shfl_xor(am, 2));
        am = fmaxf(am, 1e-4f);
        float scale = am / FP8_MAX;     // exact reference scale (IEEE div)
        float inv   = FP8_MAX / am;
#pragma unroll
        for (int n = 0; n < 4; ++n) {
            floatx2 a0 = fp8_qdq2(v[2*n].x*inv,   v[2*n].y*inv);
            floatx2 a1 = fp8_qdq2(v[2*n].z*inv,   v[2*n].w*inv);
            floatx2 a2 = fp8_qdq2(v[2*n+1].x*inv, v[2*n+1].y*inv);
            floatx2 a3 = fp8_qdq2(v[2*n+1].z*inv, v[2*n+1].w*inv);
            q4[n].x = f2bf(a0[0]*scale) | (f2bf(a0[1]*scale) << 16);
            q4[n].y = f2bf(a1[0]*scale) | (f2bf(a1[1]*scale) << 16);
            q4[n].z = f2bf(a2[0]*scale) | (f2bf(a2[1]*scale) << 16);
            q4[n].w = f2bf(a3[0]*scale) | (f2bf(a3[1]*scale) << 16);
        }
    };
    // As write: swizzled ds_write from quant regs; k-half hb only.
    auto writeA = [&](int hb) {
        if ((aq >> 1) == hb) {
#pragma unroll
            for (int n = 0; n < 4; ++n) {
                int slot = (aq & 1) * 4 + n;
                *reinterpret_cast<uint4*>(
                    As + ar * 128 + ((slot ^ (ar & 7)) << 4)) = q4[n];
            }
        }
    };

    // ---- prologue -------------------------------------------------------
    float bv[4];
#pragma unroll
    for (int ni = 0; ni < 4; ++ni)
        bv[ni] = bias[tN * 128 + wn * 64 + ni * 16 + (lane & 15)];

    loadX(0);
    // stage whole B panel: 128 chunks of 1KB (chunk c == f-row c); linear LDS
    // dest, pre-swizzled per-lane global source (rule #21 both-sides).
#pragma unroll
    for (int i = 0; i < 16; ++i) {
        int c  = wid * 16 + i;
        int kc = (lane >> 3) * 8 + ((lane & 7) ^ (c & 7));   // source k-chunk
        async_copy16(Bs + c * 1024,
                     (const char*)(Wb + (size_t)c * K) + kc * 16);
    }
    quantX();          // consumes X qb0 (MUST precede loadX(1) — v is reused)
    loadX(1);          // qb1 in flight into v
    asm volatile("s_waitcnt vmcnt(0)" ::: "memory");   // B panel + qb1 landed
    __builtin_amdgcn_s_barrier();

    // ---- main: 8 M-tiles x 8 k-steps; barriers wait lgkmcnt ONLY ---------
    for (int t = 0; t < 8; ++t) {
#pragma unroll
        for (int s = 0; s < 8; ++s) {
            // barrier 1: previous step's LDS reads landed -> As writable
            asm volatile("s_waitcnt lgkmcnt(0)" ::: "memory");
            __builtin_amdgcn_s_barrier();
            writeA(s & 1);
            // barrier 2: As writes visible to all waves
            asm volatile("s_waitcnt lgkmcnt(0)" ::: "memory");
            __builtin_amdgcn_s_barrier();
            // MFMA on k-step s (k = s*64 .. +64)
#pragma unroll
            for (int ks = 0; ks < 2; ++ks) {
                bf16x8 a[2], b[4];
#pragma unroll
                for (int mi = 0; mi < 2; ++mi) {
                    int r = wm * 32 + mi * 16 + (lane & 15);
                    a[mi] = *reinterpret_cast<const bf16x8*>(
                        As + r * 128 + ((((ks << 2) | (lane >> 4)) ^ (r & 7)) << 4));
                }
#pragma unroll
                for (int ni = 0; ni < 4; ++ni) {
                    int f = wn * 64 + ni * 16 + (lane & 15);
                    b[ni] = *reinterpret_cast<const bf16x8*>(
                        Bs + f * 1024 + s * 128
                           + ((((ks << 2) | (lane >> 4)) ^ (f & 7)) << 4));
                }
#pragma unroll
                for (int mi = 0; mi < 2; ++mi)
#pragma unroll
                    for (int ni = 0; ni < 4; ++ni)
                        acc[mi][ni] = __builtin_amdgcn_mfma_f32_16x16x32_bf16(
                            a[mi], b[ni], acc[mi][ni], 0, 0, 0);
            }
            // after MFMA issue: quant pipeline advance (odd steps)
            if (s & 1) {
                int qn = t * 4 + ((s + 1) >> 1);    // next quant block
                if (qn < 32) {
                    quantX();                        // consumes v (loaded 2 steps ago)
                    if (qn + 1 < 32) loadX(qn + 1);  // refill v, 2 steps ahead
                }
            }
        }
        // ---- M-tile epilogue: store C + bias, reset acc ------------------
        {
            int r0 = t * 128 + wm * 32 + ((lane >> 4) << 2);
            int c0 = wn * 64 + (lane & 15);
#pragma unroll
            for (int ni = 0; ni < 4; ++ni) {
#pragma unroll
                for (int mi = 0; mi < 2; ++mi) {
#pragma unroll
                    for (int e = 0; e < 4; ++e)
                        Cb[(size_t)(r0 + mi * 16 + e) * N + c0 + ni * 16] =
                            acc[mi][ni][e] + bv[ni];
                }
            }
#pragma unroll
            for (int mi = 0; mi < 2; ++mi)
#pragma unroll
                for (int ni = 0; ni < 4; ++ni)
                    acc[mi][ni] = floatx4{0.f, 0.f, 0.f, 0.f};
        }
    }
}

// ---------------------------------------------------------------------------
extern "C" void kernel_launch(void* const* d_in, const int* in_sizes, int n_in,
                              void* d_out, int out_size, void* d_ws, size_t ws_size,
                              hipStream_t stream) {
    const float* X    = (const float*)d_in[0];
    const float* W    = (const float*)d_in[1];
    const float* bias = (const float*)d_in[2];
    const int K = 512;
    const int M = in_sizes[0] / K;   // 65536
    const int mgroups = M >> 10;     // 1024 rows per block

    __hip_bfloat16* Wt = (__hip_bfloat16*)d_ws;   // 512*512*2 = 512 KB

    wdq_kernel<<<dim3(512), dim3(128), 0, stream>>>(W, Wt);
    fused_gemm<<<dim3(mgroups * 4), dim3(512), 0, stream>>>(
        X, Wt, bias, (float*)d_out, M);
}

// Round 7
// 97.944 us; speedup vs baseline: 1.3012x; 1.3012x over previous
//
#include <hip/hip_runtime.h>
#include <hip/hip_bf16.h>

typedef __attribute__((ext_vector_type(4))) float  floatx4;
typedef __attribute__((ext_vector_type(2))) float  floatx2;
typedef __attribute__((ext_vector_type(8))) __bf16 bf16x8;

#define FP8_MAX 448.0f

// HW OCP e4m3fn round-trip (RNE), matches ml_dtypes float8_e4m3fn for |v|<=448
__device__ __forceinline__ floatx2 fp8_qdq2(float a, float b) {
    int p = __builtin_amdgcn_cvt_pk_fp8_f32(a, b, 0, false);
    return __builtin_amdgcn_cvt_pk_f32_fp8(p, false);
}

__device__ __forceinline__ unsigned int f2bf(float f) {
    union { __hip_bfloat16 h; unsigned short u; } cv;
    cv.h = __float2bfloat16(f);
    return (unsigned int)cv.u;
}

__device__ __forceinline__ void async_copy16(void* lds, const void* g) {
    __builtin_amdgcn_global_load_lds(
        (const __attribute__((address_space(1))) unsigned int*)g,
        (__attribute__((address_space(3))) unsigned int*)lds, 16, 0, 0);
}

// ---------------------------------------------------------------------------
// Kernel 1: dequantize W [D=512][F=512] (quant blocks of 128 along F),
//           write transposed bf16 Wt [F=512][D=512].
__global__ void wdq_kernel(const float* __restrict__ W,
                           __hip_bfloat16* __restrict__ Wt) {
    const int D = 512, F = 512;
    int d = blockIdx.x;
    int t = threadIdx.x;
    float4 v = *reinterpret_cast<const float4*>(W + (size_t)d * F + t * 4);
    float am = fmaxf(fmaxf(fabsf(v.x), fabsf(v.y)), fmaxf(fabsf(v.z), fabsf(v.w)));
#pragma unroll
    for (int s = 16; s >= 1; s >>= 1) am = fmaxf(am, __shfl_xor(am, s));
    float scale = fmaxf(am, 1e-4f) / FP8_MAX;
    floatx2 d01 = fp8_qdq2(v.x / scale, v.y / scale);
    floatx2 d23 = fp8_qdq2(v.z / scale, v.w / scale);
    int f0 = t * 4;
    Wt[(size_t)(f0 + 0) * D + d] = __float2bfloat16(d01[0] * scale);
    Wt[(size_t)(f0 + 1) * D + d] = __float2bfloat16(d01[1] * scale);
    Wt[(size_t)(f0 + 2) * D + d] = __float2bfloat16(d23[0] * scale);
    Wt[(size_t)(f0 + 3) * D + d] = __float2bfloat16(d23[1] * scale);
}

// ---------------------------------------------------------------------------
// Kernel 2 (fused, all-DMA counted-vmcnt pipeline).
// 256 blocks (1/CU), 512 thr = 8 waves (2M x 4N; wave tile 32x64).
// Per block: 8 M-tiles x 64 rows, BN=256 (tN in {0,1}), K=512 in 8 steps/tile.
// LDS: Xf[2][64][128]f32 (64KB, X staged raw) + Bs[2][256][64]bf16 (64KB)
//      + As[2][64][64]bf16 (16KB quantized A) = 144 KB.
// Per step g: issue Bs(g+1) DMA; odd g: quant(qb) from Xf + issue Xf(qb+2);
// writeA(g+1); 16 MFMA/wave; tail: counted vmcnt (NEVER drains the Xf
// prefetch except where exact), lgkmcnt(0), s_barrier.
__global__ __launch_bounds__(512, 1) void fused_gemm(
        const float* __restrict__ X,             // [M][512] f32
        const __hip_bfloat16* __restrict__ Wt,   // [512 f][512 k] bf16
        const float* __restrict__ bias,          // [512]
        float* __restrict__ C, int M) {
    const int K = 512, N = 512;
    __shared__ char Xf[2][32768];   // [64 r][32 slot16B] f32, slot ^= r&7
    __shared__ char Bs[2][32768];   // [256 f][8 slot16B] bf16, slot ^= f&7
    __shared__ char As[2][8192];    // [64 r][8 slot16B] bf16, slot ^= r&7

    // XCD-chunked bijective swizzle: 32 consecutive tiles per XCD -> the two
    // tN panels of each mg share one XCD's L2 (X fetched once from HBM).
    int bx   = blockIdx.x;
    int tile = (bx & 7) * 32 + (bx >> 3);      // 256 = 8 x 32, bijective
    int tN   = tile & 1;                        // N-panel of 256
    int mg   = tile >> 1;                       // [0,128): 512 rows each

    int tid = threadIdx.x, wid = tid >> 6, lane = tid & 63;
    int wm = wid >> 2, wn = wid & 3;            // wave grid 2(M) x 4(N)
    int qr = tid >> 3, qq = tid & 7;            // quant: 8 thr/row, 16 f32 each

    const char* Xbase = (const char*)(X + (size_t)mg * 512 * K);
    const char* Wbase = (const char*)(Wt + (size_t)tN * 256 * K);
    float* Cb = C + (size_t)mg * 512 * N + tN * 256;

    float4 xv[4];       // 16 f32 of one quant-block row-slice
    uint4  q4[2];       // 16 bf16 quantized
    floatx4 acc[2][4] = {};

    // ---- bias (pinned before DMAs so vmcnt counts stay derivable) ----
    float bv[4];
#pragma unroll
    for (int ni = 0; ni < 4; ++ni)
        bv[ni] = bias[tN * 256 + wn * 64 + ni * 16 + (lane & 15)];
    __builtin_amdgcn_sched_barrier(0);

    // qb in [0,32): M-subtile T=qb>>2 (64 rows), k-block kb=qb&3 (128 k)
    auto issueXf = [&](int buf, int qb) {
        const char* base = Xbase + ((size_t)(qb >> 2) * 64 * K + (qb & 3) * 128) * 4;
#pragma unroll
        for (int cc = 0; cc < 4; ++cc) {
            int c = wid * 4 + cc;               // 1KB chunk = rows 2c,2c+1
            int r = 2 * c + (lane >> 5);
            int d = lane & 31;                  // dest 16B slot (linear)
            async_copy16(Xf[buf] + c * 1024,
                         base + (size_t)r * (K * 4) + ((d ^ (r & 7)) << 4));
        }
    };
    auto issueBs = [&](int buf, int ksi) {      // ksi = k-step in [0,8)
        const char* base = Wbase + ksi * 64 * 2;
#pragma unroll
        for (int cc = 0; cc < 4; ++cc) {
            int c  = wid * 4 + cc;              // 1KB chunk = 8 f-rows
            int rr = 8 * c + (lane >> 3);
            int d  = lane & 7;
            async_copy16(Bs[buf] + c * 1024,
                         base + (size_t)rr * (K * 2) + ((d ^ (rr & 7)) << 4));
        }
    };
    auto quantX = [&](int buf) {
        const char* xb = Xf[buf] + qr * 512;
        int r7 = qr & 7;
#pragma unroll
        for (int j = 0; j < 4; ++j)
            xv[j] = *reinterpret_cast<const float4*>(
                xb + ((((qq << 2) + j) ^ r7) << 4));
        float am = 0.f;
#pragma unroll
        for (int j = 0; j < 4; ++j)
            am = fmaxf(am, fmaxf(fmaxf(fabsf(xv[j].x), fabsf(xv[j].y)),
                                 fmaxf(fabsf(xv[j].z), fabsf(xv[j].w))));
        am = fmaxf(am, __shfl_xor(am, 1));
        am = fmaxf(am, __shfl_xor(am, 2));
        am = fmaxf(am, __shfl_xor(am, 4));
        am = fmaxf(am, 1e-4f);
        float scale = am / FP8_MAX;             // exact reference scale
        float inv   = FP8_MAX / am;
#pragma unroll
        for (int n = 0; n < 2; ++n) {
            floatx2 a0 = fp8_qdq2(xv[2*n].x*inv,   xv[2*n].y*inv);
            floatx2 a1 = fp8_qdq2(xv[2*n].z*inv,   xv[2*n].w*inv);
            floatx2 a2 = fp8_qdq2(xv[2*n+1].x*inv, xv[2*n+1].y*inv);
            floatx2 a3 = fp8_qdq2(xv[2*n+1].z*inv, xv[2*n+1].w*inv);
            q4[n].x = f2bf(a0[0]*scale) | (f2bf(a0[1]*scale) << 16);
            q4[n].y = f2bf(a1[0]*scale) | (f2bf(a1[1]*scale) << 16);
            q4[n].z = f2bf(a2[0]*scale) | (f2bf(a2[1]*scale) << 16);
            q4[n].w = f2bf(a3[0]*scale) | (f2bf(a3[1]*scale) << 16);
        }
    };
    // write k-half h of q4 into As[buf] (h matched against thread's qq)
    auto writeA = [&](int buf, int h) {
        if ((qq >> 2) == h) {
            int s0 = (qq & 3) * 2, r7 = qr & 7;
            *reinterpret_cast<uint4*>(As[buf] + qr * 128 + (((s0)     ^ r7) << 4)) = q4[0];
            *reinterpret_cast<uint4*>(As[buf] + qr * 128 + (((s0 + 1) ^ r7) << 4)) = q4[1];
        }
    };
    auto mfmaStep = [&](int buf) {
#pragma unroll
        for (int ks = 0; ks < 2; ++ks) {
            int sl = ks * 4 + (lane >> 4);
            bf16x8 a[2], b[4];
#pragma unroll
            for (int mi = 0; mi < 2; ++mi) {
                int r = wm * 32 + mi * 16 + (lane & 15);
                a[mi] = *reinterpret_cast<const bf16x8*>(
                    As[buf] + r * 128 + ((sl ^ (r & 7)) << 4));
            }
#pragma unroll
            for (int ni = 0; ni < 4; ++ni) {
                int f = wn * 64 + ni * 16 + (lane & 15);
                b[ni] = *reinterpret_cast<const bf16x8*>(
                    Bs[buf] + f * 128 + ((sl ^ (f & 7)) << 4));
            }
#pragma unroll
            for (int mi = 0; mi < 2; ++mi)
#pragma unroll
                for (int ni = 0; ni < 4; ++ni)
                    acc[mi][ni] = __builtin_amdgcn_mfma_f32_16x16x32_bf16(
                        a[mi], b[ni], acc[mi][ni], 0, 0, 0);
        }
    };
    auto storeC = [&](int T) {
#pragma unroll
        for (int ni = 0; ni < 4; ++ni) {
            int col = wn * 64 + ni * 16 + (lane & 15);
#pragma unroll
            for (int mi = 0; mi < 2; ++mi) {
                int r0 = T * 64 + wm * 32 + mi * 16 + ((lane >> 4) << 2);
#pragma unroll
                for (int e = 0; e < 4; ++e)
                    Cb[(size_t)(r0 + e) * N + col] = acc[mi][ni][e] + bv[ni];
            }
        }
#pragma unroll
        for (int mi = 0; mi < 2; ++mi)
#pragma unroll
            for (int ni = 0; ni < 4; ++ni)
                acc[mi][ni] = floatx4{0.f, 0.f, 0.f, 0.f};
    };

    // ---- prologue: FIFO = [bias.4][Xf0.4][Bs0.4] ------------------------
    issueXf(0, 0);
    issueBs(0, 0);
    asm volatile("s_waitcnt vmcnt(4)" ::: "memory");   // bias+Xf0 done, Bs floats
    __builtin_amdgcn_s_barrier();
    quantX(0);                                         // q4 = qb0
    writeA(0, 0);                                      // half0 -> As[0]
    issueXf(1, 1);                                     // qb1 in flight
    asm volatile("s_waitcnt vmcnt(4)" ::: "memory");   // Bs0 done, Xf1 floats
    asm volatile("s_waitcnt lgkmcnt(0)" ::: "memory");
    __builtin_amdgcn_s_barrier();

    // ---- main: g = t*8+s, 64 steps, 1 barrier each ----------------------
#pragma unroll 1
    for (int t = 0; t < 8; ++t) {
#pragma unroll
        for (int s = 0; s < 8; ++s) {
            int g = t * 8 + s, cur = g & 1, nxt = cur ^ 1;
            if (g < 63) issueBs(nxt, (s + 1) & 7);
            bool xf_issued = false;
            if (s & 1) {
                int Q = g >> 1;                 // current qb index
                if (Q + 1 < 32) quantX((Q + 1) & 1);    // q4 = qb Q+1
                if (Q + 2 < 32) { issueXf((Q + 2) & 1, Q + 2); xf_issued = true; }
                if (Q + 1 < 32) writeA(nxt, 0); // half0 of qb Q+1
            } else {
                writeA(nxt, 1);                 // half1 of current qb
            }
            mfmaStep(cur);
            if (s == 7) storeC(t);
            if (g < 63) {
                if ((s & 1) == 0) {
                    asm volatile("s_waitcnt vmcnt(0)" ::: "memory");
                } else if (s == 7) {
                    // FIFO: [Bs.4][Xf.4][st.32] -> wait oldest 4 (Bs)
                    asm volatile("s_waitcnt vmcnt(36)" ::: "memory");
                } else if (xf_issued) {
                    // FIFO: [Bs.4][Xf.4] -> wait Bs, leave Xf prefetch
                    asm volatile("s_waitcnt vmcnt(4)" ::: "memory");
                } else {
                    asm volatile("s_waitcnt vmcnt(0)" ::: "memory");
                }
                asm volatile("s_waitcnt lgkmcnt(0)" ::: "memory");
                __builtin_amdgcn_s_barrier();
            }
        }
    }
}

// ---------------------------------------------------------------------------
extern "C" void kernel_launch(void* const* d_in, const int* in_sizes, int n_in,
                              void* d_out, int out_size, void* d_ws, size_t ws_size,
                              hipStream_t stream) {
    const float* X    = (const float*)d_in[0];
    const float* W    = (const float*)d_in[1];
    const float* bias = (const float*)d_in[2];
    const int K = 512;
    const int M = in_sizes[0] / K;   // 65536

    __hip_bfloat16* Wt = (__hip_bfloat16*)d_ws;   // 512*512*2 = 512 KB

    wdq_kernel<<<dim3(512), dim3(128), 0, stream>>>(W, Wt);
    fused_gemm<<<dim3(256), dim3(512), 0, stream>>>(
        X, Wt, bias, (float*)d_out, M);
}